// Round 2
// baseline (2383.429 us; speedup 1.0000x reference)
//
#include <hip/hip_runtime.h>
#include <cstddef>

// Problem constants (reference: B=4, S=2048, D=1024, H=16, HD=64)
constexpr int Bn  = 4;
constexpr int Sn  = 2048;
constexpr int Dn  = 1024;
constexpr int Hn  = 16;
constexpr int HDn = 64;

// ---------------------------------------------------------------------------
// GEMM: out = A(M x K) @ W(K x N) + bias
// MODE 0: out row-major [M, N]                      (final projection)
// MODE 1: out as [B, H, S, HD]  (n -> (h, hd))      (QKV projections)
// Tiling: 64x64 block tile, 256 threads, 4x4 per thread, K-chunk = 16.
// ---------------------------------------------------------------------------
template <int MODE>
__global__ __launch_bounds__(256) void gemm_bias_k(
    const float* __restrict__ A, const float* __restrict__ W,
    const float* __restrict__ bias, float* __restrict__ out)
{
    constexpr int K = Dn;
    constexpr int N = Dn;
    __shared__ float As[16][68];  // As[kk][m], pad 68 keeps float4 alignment & banks spread
    __shared__ float Ws[16][68];  // Ws[kk][n]

    const int tid = threadIdx.x;
    const int tx  = tid & 15;
    const int ty  = tid >> 4;
    const int m0  = blockIdx.x * 64;
    const int n0  = blockIdx.y * 64;

    float acc[4][4] = {};

    for (int k0 = 0; k0 < K; k0 += 16) {
        // A tile: 64 rows x 16 k. One float4 per thread; scatter-transpose into LDS.
        {
            const int m  = tid >> 2;
            const int c0 = (tid & 3) << 2;
            float4 t4 = *(const float4*)(A + (size_t)(m0 + m) * K + k0 + c0);
            As[c0 + 0][m] = t4.x;
            As[c0 + 1][m] = t4.y;
            As[c0 + 2][m] = t4.z;
            As[c0 + 3][m] = t4.w;
        }
        // W tile: 16 k x 64 n. One float4 per thread, coalesced rows.
        {
            const int kk = tid >> 4;
            const int c0 = (tid & 15) << 2;
            *(float4*)&Ws[kk][c0] = *(const float4*)(W + (size_t)(k0 + kk) * N + n0 + c0);
        }
        __syncthreads();

        #pragma unroll
        for (int kk = 0; kk < 16; ++kk) {
            float4 a4 = *(const float4*)&As[kk][ty << 2];
            float4 b4 = *(const float4*)&Ws[kk][tx << 2];
            float av[4] = {a4.x, a4.y, a4.z, a4.w};
            float bv[4] = {b4.x, b4.y, b4.z, b4.w};
            #pragma unroll
            for (int i = 0; i < 4; ++i)
                #pragma unroll
                for (int j = 0; j < 4; ++j)
                    acc[i][j] += av[i] * bv[j];
        }
        __syncthreads();
    }

    #pragma unroll
    for (int i = 0; i < 4; ++i) {
        const int m = m0 + (ty << 2) + i;
        float4 r;
        r.x = acc[i][0] + bias[n0 + (tx << 2) + 0];
        r.y = acc[i][1] + bias[n0 + (tx << 2) + 1];
        r.z = acc[i][2] + bias[n0 + (tx << 2) + 2];
        r.w = acc[i][3] + bias[n0 + (tx << 2) + 3];
        if (MODE == 0) {
            *(float4*)(out + (size_t)m * N + n0 + (tx << 2)) = r;
        } else {
            // n-tile width 64 == HD, so one tile == one head.
            const int b = m >> 11;          // / Sn
            const int s = m & (Sn - 1);
            const int h = n0 >> 6;          // / HDn
            *(float4*)(out + (size_t)b * Sn * Dn + (size_t)h * Sn * HDn +
                       (size_t)s * HDn + (tx << 2)) = r;
        }
    }
}

// ---------------------------------------------------------------------------
// Flash-style attention, fp32.
// Q/K/V layout: [B*H, S, HD]. One block = one (b,h) and a 64-query tile.
// 64-key chunks; online softmax (running m, l) per query row.
// energy = (q.k)/8 * mod[b,q,k]; masked QUERY rows forced to -1e10
// (-> uniform softmax -> mean(V), matching reference).
// K and V share one LDS buffer (V load overwrites K after QK^T).
// Modifier tile is staged through Ss, then overwritten in place by scores.
// ---------------------------------------------------------------------------
__global__ __launch_bounds__(256) void attn_k(
    const float* __restrict__ Q, const float* __restrict__ Km,
    const float* __restrict__ Vm, const int* __restrict__ kpm,
    const float* __restrict__ mod, float* __restrict__ att)
{
    __shared__ float Qs[64][68];
    __shared__ float KVs[64][68];
    __shared__ float Ss[64][68];
    __shared__ float row_m[64], row_l[64], row_alpha[64];

    const int tid = threadIdx.x;
    const int tx  = tid & 15;
    const int ty  = tid >> 4;
    const int bh  = blockIdx.x;      // b*H + h
    const int b   = bh >> 4;
    const int h   = bh & 15;
    const int q0  = blockIdx.y * 64;
    const size_t hb = (size_t)bh * Sn * HDn;

    // Load Q tile (64 x 64 floats)
    #pragma unroll
    for (int it = 0; it < 4; ++it) {
        const int idx = it * 256 + tid;
        const int r = idx >> 4, c = (idx & 15) << 2;
        *(float4*)&Qs[r][c] = *(const float4*)(Q + hb + (size_t)(q0 + r) * HDn + c);
    }
    if (tid < 64) { row_m[tid] = -1e30f; row_l[tid] = 0.0f; }

    // key_padding_mask arrives as int32 (jax bool -> integer -> const int*)
    bool qmask[4];
    #pragma unroll
    for (int i = 0; i < 4; ++i)
        qmask[i] = kpm[(size_t)b * Sn + q0 + (ty << 2) + i] != 0;

    float accO[4][4] = {};
    __syncthreads();

    for (int k0 = 0; k0 < Sn; k0 += 64) {
        // Load K tile into KVs, modifier tile into Ss.
        #pragma unroll
        for (int it = 0; it < 4; ++it) {
            const int idx = it * 256 + tid;
            const int r = idx >> 4, c = (idx & 15) << 2;
            *(float4*)&KVs[r][c] = *(const float4*)(Km + hb + (size_t)(k0 + r) * HDn + c);
            *(float4*)&Ss[r][c]  = *(const float4*)(mod + (size_t)b * Sn * Sn +
                                                    (size_t)(q0 + r) * Sn + k0 + c);
        }
        __syncthreads();

        // S = Q K^T (4x4 scores per thread), scale + modifier + query mask.
        float sacc[4][4] = {};
        for (int dd = 0; dd < 64; ++dd) {
            float qv[4], kv[4];
            #pragma unroll
            for (int i = 0; i < 4; ++i) qv[i] = Qs[(ty << 2) + i][dd];
            #pragma unroll
            for (int j = 0; j < 4; ++j) kv[j] = KVs[(tx << 2) + j][dd];
            #pragma unroll
            for (int i = 0; i < 4; ++i)
                #pragma unroll
                for (int j = 0; j < 4; ++j)
                    sacc[i][j] += qv[i] * kv[j];
        }
        #pragma unroll
        for (int i = 0; i < 4; ++i)
            #pragma unroll
            for (int j = 0; j < 4; ++j) {
                // Each thread owns cell (qy,kx): reading mod then writing score
                // to the same LDS cell is race-free.
                const float sc = sacc[i][j] * 0.125f * Ss[(ty << 2) + i][(tx << 2) + j];
                Ss[(ty << 2) + i][(tx << 2) + j] = qmask[i] ? -1e10f : sc;
            }
        __syncthreads();

        // Load V tile (overwrites K — QK^T is done). Threads 0..63 also run
        // the per-row online-softmax update on Ss (disjoint memory).
        #pragma unroll
        for (int it = 0; it < 4; ++it) {
            const int idx = it * 256 + tid;
            const int r = idx >> 4, c = (idx & 15) << 2;
            *(float4*)&KVs[r][c] = *(const float4*)(Vm + hb + (size_t)(k0 + r) * HDn + c);
        }
        if (tid < 64) {
            const float mold = row_m[tid];
            float cmax = -1e30f;
            for (int j = 0; j < 64; ++j) cmax = fmaxf(cmax, Ss[tid][j]);
            const float mnew  = fmaxf(mold, cmax);
            const float alpha = __expf(mold - mnew);
            float lsum = 0.0f;
            for (int j = 0; j < 64; ++j) {
                const float p = __expf(Ss[tid][j] - mnew);
                Ss[tid][j] = p;
                lsum += p;
            }
            row_m[tid]     = mnew;
            row_l[tid]     = row_l[tid] * alpha + lsum;
            row_alpha[tid] = alpha;
        }
        __syncthreads();

        // O = O*alpha + P V
        #pragma unroll
        for (int i = 0; i < 4; ++i) {
            const float al = row_alpha[(ty << 2) + i];
            #pragma unroll
            for (int j = 0; j < 4; ++j) accO[i][j] *= al;
        }
        for (int kk = 0; kk < 64; ++kk) {
            float pv[4], vv[4];
            #pragma unroll
            for (int i = 0; i < 4; ++i) pv[i] = Ss[(ty << 2) + i][kk];
            #pragma unroll
            for (int j = 0; j < 4; ++j) vv[j] = KVs[kk][(tx << 2) + j];
            #pragma unroll
            for (int i = 0; i < 4; ++i)
                #pragma unroll
                for (int j = 0; j < 4; ++j)
                    accO[i][j] += pv[i] * vv[j];
        }
        __syncthreads();
    }

    // Normalize and write attention output in [B, S, D] row-major
    // (column = h*HD + hd) so the final GEMM consumes it directly.
    #pragma unroll
    for (int i = 0; i < 4; ++i) {
        const int qy  = (ty << 2) + i;
        const float inv = 1.0f / row_l[qy];
        float4 r;
        r.x = accO[i][0] * inv;
        r.y = accO[i][1] * inv;
        r.z = accO[i][2] * inv;
        r.w = accO[i][3] * inv;
        *(float4*)(att + (size_t)(b * Sn + q0 + qy) * Dn + h * HDn + (tx << 2)) = r;
    }
}

// ---------------------------------------------------------------------------
// Launch
// ---------------------------------------------------------------------------
extern "C" void kernel_launch(void* const* d_in, const int* in_sizes, int n_in,
                              void* d_out, int out_size, void* d_ws, size_t ws_size,
                              hipStream_t stream) {
    const float* x   = (const float*)d_in[0];
    const int*   kpm = (const int*)d_in[1];   // jax bool -> integer -> int32
    const float* mod = (const float*)d_in[2];
    const float* Wq  = (const float*)d_in[3];
    const float* bq  = (const float*)d_in[4];
    const float* Wk  = (const float*)d_in[5];
    const float* bk  = (const float*)d_in[6];
    const float* Wv  = (const float*)d_in[7];
    const float* bv  = (const float*)d_in[8];
    const float* Wo  = (const float*)d_in[9];
    const float* bo  = (const float*)d_in[10];
    float* out = (float*)d_out;

    // Workspace: Q, K, V ([B,H,S,HD]) + attention output ([B,S,D]) = 128 MiB fp32.
    float* ws = (float*)d_ws;
    const size_t sz = (size_t)Bn * Sn * Dn;  // 8388608
    float* qb = ws;
    float* kb = ws + sz;
    float* vb = ws + 2 * sz;
    float* ab = ws + 3 * sz;

    const dim3 gemm_grid(128, 16);   // (M/64, N/64) for M=8192, N=1024
    const dim3 attn_grid(Bn * Hn, Sn / 64);

    gemm_bias_k<1><<<gemm_grid, 256, 0, stream>>>(x, Wq, bq, qb);
    gemm_bias_k<1><<<gemm_grid, 256, 0, stream>>>(x, Wk, bk, kb);
    gemm_bias_k<1><<<gemm_grid, 256, 0, stream>>>(x, Wv, bv, vb);
    attn_k<<<attn_grid, 256, 0, stream>>>(qb, kb, vb, kpm, mod, ab);
    gemm_bias_k<0><<<gemm_grid, 256, 0, stream>>>(ab, Wo, bo, out);
}

// Round 3
// 724.714 us; speedup vs baseline: 3.2888x; 3.2888x over previous
//
#include <hip/hip_runtime.h>
#include <cstddef>

// Problem constants: B=4, S=2048, D=1024, H=16, HD=64
constexpr int Bn  = 4;
constexpr int Sn  = 2048;
constexpr int Dn  = 1024;
constexpr int Hn  = 16;
constexpr int HDn = 64;

typedef __bf16 bf16;
typedef __attribute__((ext_vector_type(8))) __bf16 bf16x8;
typedef __attribute__((ext_vector_type(4))) float  f32x4;

// ---------------------------------------------------------------------------
// Elementwise fp32 -> bf16 (x and att staging)
// ---------------------------------------------------------------------------
__global__ __launch_bounds__(256) void conv_f32_bf16_k(
    const float* __restrict__ in, bf16* __restrict__ out, int n)
{
    int i = (blockIdx.x * 256 + threadIdx.x) * 4;
    if (i + 3 < n) {
        float4 v = *(const float4*)(in + i);
        bf16 o[4] = {(bf16)v.x, (bf16)v.y, (bf16)v.z, (bf16)v.w};
        *(ulong1*)(out + i) = *(ulong1*)o;  // 8B store
    }
}

// ---------------------------------------------------------------------------
// Weight transpose + convert: W[k][n] fp32 -> Wt[n][k] bf16. 64x64 tiles.
// blockIdx.z selects which of the 4 weight matrices.
// ---------------------------------------------------------------------------
__global__ __launch_bounds__(256) void conv_wt_k(
    const float* __restrict__ w0, const float* __restrict__ w1,
    const float* __restrict__ w2, const float* __restrict__ w3,
    bf16* __restrict__ o0, bf16* __restrict__ o1,
    bf16* __restrict__ o2, bf16* __restrict__ o3)
{
    const float* W = (blockIdx.z == 0) ? w0 : (blockIdx.z == 1) ? w1
                   : (blockIdx.z == 2) ? w2 : w3;
    bf16* O = (blockIdx.z == 0) ? o0 : (blockIdx.z == 1) ? o1
            : (blockIdx.z == 2) ? o2 : o3;
    __shared__ float t[64][65];
    const int tid = threadIdx.x;
    const int k0 = blockIdx.x * 64;   // row of W (k-dim)
    const int n0 = blockIdx.y * 64;   // col of W (n-dim)
    #pragma unroll
    for (int p = 0; p < 16; ++p) {
        const int idx = p * 256 + tid;
        const int r = idx >> 6, c = idx & 63;
        t[r][c] = W[(size_t)(k0 + r) * Dn + n0 + c];
    }
    __syncthreads();
    #pragma unroll
    for (int p = 0; p < 16; ++p) {
        const int idx = p * 256 + tid;
        const int r = idx >> 6, c = idx & 63;   // r: n-offset, c: k-offset
        O[(size_t)(n0 + r) * Dn + k0 + c] = (bf16)t[c][r];
    }
}

// ---------------------------------------------------------------------------
// bf16 MFMA GEMM: out = A(8192 x 1024) @ Bt^T + bias, Bt is [N][K] bf16.
// Block: 256 thr / 4 waves; tile 64x64, BK=64. Wave w owns rows w*16..w*16+15.
// MFMA 16x16x32 bf16; fragment maps (verified):
//   A[m=lane&15][k=(lane>>4)*8+j], B[k=(lane>>4)*8+j][n=lane&15],
//   C/D: col=lane&15, row=(lane>>4)*4+reg.
// MODE 0: fp32 out [M][N] (final projection)
// MODE 1: bf16 out [b,h,s,hd]  (Q, K)
// MODE 2: bf16 out [b,h,hd,s]  (V transposed for the PV B-operand)
// ---------------------------------------------------------------------------
template <int MODE>
__global__ __launch_bounds__(256) void gemm_bf16_k(
    const bf16* __restrict__ A, const bf16* __restrict__ Bt,
    const float* __restrict__ bias, void* __restrict__ outv)
{
    __shared__ __align__(16) bf16 As[64][72];
    __shared__ __align__(16) bf16 Bs[64][72];

    const int tid  = threadIdx.x;
    const int w    = tid >> 6;
    const int lane = tid & 63;
    const int quad = lane >> 4;
    const int l15  = lane & 15;
    const int m0   = blockIdx.x * 64;
    const int n0   = blockIdx.y * 64;

    f32x4 acc[4] = {};

    for (int k0 = 0; k0 < Dn; k0 += 64) {
        #pragma unroll
        for (int p = 0; p < 2; ++p) {
            const int c = p * 256 + tid;
            const int r = c >> 3, off = (c & 7) * 8;
            *(bf16x8*)&As[r][off] =
                *(const bf16x8*)(A + (size_t)(m0 + r) * Dn + k0 + off);
            *(bf16x8*)&Bs[r][off] =
                *(const bf16x8*)(Bt + (size_t)(n0 + r) * Dn + k0 + off);
        }
        __syncthreads();
        #pragma unroll
        for (int ks = 0; ks < 64; ks += 32) {
            bf16x8 af = *(const bf16x8*)&As[w * 16 + l15][ks + quad * 8];
            #pragma unroll
            for (int ct = 0; ct < 4; ++ct) {
                bf16x8 bfr = *(const bf16x8*)&Bs[ct * 16 + l15][ks + quad * 8];
                acc[ct] = __builtin_amdgcn_mfma_f32_16x16x32_bf16(af, bfr, acc[ct], 0, 0, 0);
            }
        }
        __syncthreads();
    }

    #pragma unroll
    for (int ct = 0; ct < 4; ++ct) {
        const int c = n0 + ct * 16 + l15;
        const float bv = bias[c];
        #pragma unroll
        for (int i = 0; i < 4; ++i) {
            const int m = m0 + w * 16 + quad * 4 + i;
            const float v = acc[ct][i] + bv;
            if (MODE == 0) {
                ((float*)outv)[(size_t)m * Dn + c] = v;
            } else {
                const int b = m >> 11, s = m & (Sn - 1);
                const int h = c >> 6, hd = c & 63;
                if (MODE == 1)
                    ((bf16*)outv)[(((size_t)(b * Hn + h) * Sn) + s) * HDn + hd] = (bf16)v;
                else
                    ((bf16*)outv)[(((size_t)(b * Hn + h) * HDn) + hd) * Sn + s] = (bf16)v;
            }
        }
    }
}

// ---------------------------------------------------------------------------
// Flash attention, bf16 MFMA.
// Q,K: [bh][s][hd] bf16; Vt: [bh][hd][s] bf16. Block = (bh, 64-query tile),
// 256 thr / 4 waves; wave w owns q-rows w*16..w*16+15. 64-key chunks.
// S = Q K^T via MFMA (C-layout), scale*mod*qmask in regs, online softmax with
// shfl-xor(width 16) row reductions, P relayout through LDS (wave-local rows,
// no barrier needed), PV via MFMA with Vt B-frags. Output bf16 [b][s][D].
// ---------------------------------------------------------------------------
__global__ __launch_bounds__(256) void attn_mfma_k(
    const bf16* __restrict__ Qb, const bf16* __restrict__ Kb,
    const bf16* __restrict__ Vtb, const int* __restrict__ kpm,
    const float* __restrict__ mod, bf16* __restrict__ att)
{
    __shared__ __align__(16) bf16 Qs[64][72];
    __shared__ __align__(16) bf16 Ks[64][72];
    __shared__ __align__(16) bf16 Vts[64][72];
    __shared__ __align__(16) bf16 Ps[64][72];

    const int tid  = threadIdx.x;
    const int w    = tid >> 6;
    const int lane = tid & 63;
    const int quad = lane >> 4;
    const int l15  = lane & 15;
    const int bh   = blockIdx.x;
    const int b    = bh >> 4;
    const int h    = bh & 15;
    const int q0   = blockIdx.y * 64;
    const size_t base = (size_t)bh * Sn * HDn;

    // Stage Q tile once.
    #pragma unroll
    for (int p = 0; p < 2; ++p) {
        const int c = p * 256 + tid;
        const int r = c >> 3, off = (c & 7) * 8;
        *(bf16x8*)&Qs[r][off] =
            *(const bf16x8*)(Qb + base + (size_t)(q0 + r) * HDn + off);
    }

    bool qmask[4];
    #pragma unroll
    for (int i = 0; i < 4; ++i)
        qmask[i] = kpm[(size_t)b * Sn + q0 + w * 16 + quad * 4 + i] != 0;

    float m_r[4] = {-1e30f, -1e30f, -1e30f, -1e30f};
    float l_r[4] = {};
    f32x4 O[4]   = {};
    __syncthreads();

    for (int k0 = 0; k0 < Sn; k0 += 64) {
        // Stage K chunk [key][d] and Vt chunk [d][key].
        #pragma unroll
        for (int p = 0; p < 2; ++p) {
            const int c = p * 256 + tid;
            const int r = c >> 3, off = (c & 7) * 8;
            *(bf16x8*)&Ks[r][off] =
                *(const bf16x8*)(Kb + base + (size_t)(k0 + r) * HDn + off);
            *(bf16x8*)&Vts[r][off] =
                *(const bf16x8*)(Vtb + base + (size_t)r * Sn + k0 + off);
        }
        __syncthreads();

        // QK^T -> energies in regs (C-layout: row=quad*4+i, col=ct*16+l15)
        float e[4][4];
        #pragma unroll
        for (int ct = 0; ct < 4; ++ct) {
            f32x4 s = {};
            #pragma unroll
            for (int ks = 0; ks < 64; ks += 32) {
                bf16x8 af  = *(const bf16x8*)&Qs[w * 16 + l15][ks + quad * 8];
                bf16x8 bfr = *(const bf16x8*)&Ks[ct * 16 + l15][ks + quad * 8];
                s = __builtin_amdgcn_mfma_f32_16x16x32_bf16(af, bfr, s, 0, 0, 0);
            }
            #pragma unroll
            for (int i = 0; i < 4; ++i) {
                const int row = w * 16 + quad * 4 + i;
                const float mo = mod[((size_t)b * Sn + q0 + row) * Sn + k0 + ct * 16 + l15];
                e[ct][i] = qmask[i] ? -1e10f : s[i] * 0.125f * mo;
            }
        }

        // Online softmax per row; P -> LDS (wave-local rows only).
        float alpha[4];
        #pragma unroll
        for (int i = 0; i < 4; ++i) {
            float mx = fmaxf(fmaxf(e[0][i], e[1][i]), fmaxf(e[2][i], e[3][i]));
            #pragma unroll
            for (int msk = 1; msk < 16; msk <<= 1)
                mx = fmaxf(mx, __shfl_xor(mx, msk, 16));
            const float mnew = fmaxf(m_r[i], mx);
            alpha[i] = __expf(m_r[i] - mnew);
            float rs = 0.0f;
            #pragma unroll
            for (int ct = 0; ct < 4; ++ct) {
                const float p = __expf(e[ct][i] - mnew);
                const bf16 pb = (bf16)p;
                Ps[w * 16 + quad * 4 + i][ct * 16 + l15] = pb;
                rs += (float)pb;   // sum rounded values: numerator-consistent
            }
            #pragma unroll
            for (int msk = 1; msk < 16; msk <<= 1)
                rs += __shfl_xor(rs, msk, 16);
            l_r[i] = l_r[i] * alpha[i] + rs;
            m_r[i] = mnew;
        }

        // O = O*alpha + P V   (A-frags from Ps rows this wave wrote itself)
        #pragma unroll
        for (int ct = 0; ct < 4; ++ct)
            #pragma unroll
            for (int i = 0; i < 4; ++i)
                O[ct][i] *= alpha[i];
        #pragma unroll
        for (int ks = 0; ks < 64; ks += 32) {
            bf16x8 af = *(const bf16x8*)&Ps[w * 16 + l15][ks + quad * 8];
            #pragma unroll
            for (int ct = 0; ct < 4; ++ct) {
                bf16x8 bfr = *(const bf16x8*)&Vts[ct * 16 + l15][ks + quad * 8];
                O[ct] = __builtin_amdgcn_mfma_f32_16x16x32_bf16(af, bfr, O[ct], 0, 0, 0);
            }
        }
        __syncthreads();  // protect Ks/Vts before next chunk's staging
    }

    float inv[4];
    #pragma unroll
    for (int i = 0; i < 4; ++i) inv[i] = 1.0f / l_r[i];
    #pragma unroll
    for (int ct = 0; ct < 4; ++ct)
        #pragma unroll
        for (int i = 0; i < 4; ++i) {
            const int row = q0 + w * 16 + quad * 4 + i;
            const int col = h * HDn + ct * 16 + l15;
            att[((size_t)b * Sn + row) * Dn + col] = (bf16)(O[ct][i] * inv[i]);
        }
}

// ---------------------------------------------------------------------------
// Launch
// ---------------------------------------------------------------------------
extern "C" void kernel_launch(void* const* d_in, const int* in_sizes, int n_in,
                              void* d_out, int out_size, void* d_ws, size_t ws_size,
                              hipStream_t stream) {
    const float* x   = (const float*)d_in[0];
    const int*   kpm = (const int*)d_in[1];
    const float* mod = (const float*)d_in[2];
    const float* Wq  = (const float*)d_in[3];
    const float* bq  = (const float*)d_in[4];
    const float* Wk  = (const float*)d_in[5];
    const float* bk  = (const float*)d_in[6];
    const float* Wv  = (const float*)d_in[7];
    const float* bv  = (const float*)d_in[8];
    const float* Wo  = (const float*)d_in[9];
    const float* bo  = (const float*)d_in[10];
    float* out = (float*)d_out;

    // Workspace (all bf16): xb, qb, kb, vtb, attb (8.4M each) + 4 Wt (1M each)
    bf16* ws = (bf16*)d_ws;
    const size_t sz = (size_t)Bn * Sn * Dn;   // 8388608
    const size_t wz = (size_t)Dn * Dn;        // 1048576
    bf16* xb   = ws;
    bf16* qb   = ws + sz;
    bf16* kb   = ws + 2 * sz;
    bf16* vtb  = ws + 3 * sz;
    bf16* attb = ws + 4 * sz;
    bf16* wqt  = ws + 5 * sz;
    bf16* wkt  = wqt + wz;
    bf16* wvt  = wkt + wz;
    bf16* wot  = wvt + wz;

    conv_f32_bf16_k<<<(int)(sz / 1024), 256, 0, stream>>>(x, xb, (int)sz);
    conv_wt_k<<<dim3(16, 16, 4), 256, 0, stream>>>(Wq, Wk, Wv, Wo, wqt, wkt, wvt, wot);

    const dim3 gemm_grid(128, 16);
    gemm_bf16_k<1><<<gemm_grid, 256, 0, stream>>>(xb, wqt, bq, qb);
    gemm_bf16_k<1><<<gemm_grid, 256, 0, stream>>>(xb, wkt, bk, kb);
    gemm_bf16_k<2><<<gemm_grid, 256, 0, stream>>>(xb, wvt, bv, vtb);

    attn_mfma_k<<<dim3(Bn * Hn, Sn / 64), 256, 0, stream>>>(qb, kb, vtb, kpm, mod, attb);

    gemm_bf16_k<0><<<gemm_grid, 256, 0, stream>>>(attb, wot, bo, out);
}